// Round 4
// baseline (1882.136 us; speedup 1.0000x reference)
//
#include <hip/hip_runtime.h>
#include <hip/hip_fp16.h>

// GCN: out = Ahat*(relu(Ahat*(x@W1)+b1))@W2 + b2,  Ahat = D^-1/2 (A+I) D^-1/2
// N=100000, E=1600000, IN=256, HID=128, OUT=64, fp32 in/out.
// R10 = R9 resubmit (round-3 bench died on container acquisition, not kernel):
//     keep R8's verified L2-resident column slices (FETCH 190->43MB), kill
//     R8's latency structure (wave-per-node x8 overhead, serial chains):
//   - agg = block per (128-node bucket, 16-col group), LDS f32 accumulators
//     (stride 17 pad), scatter-add via ds_add_f32. Edges come from `pairs`
//     (bucket-contiguous, dst in low 7 bits) -> no csr, no off, no per-node
//     loop. 16 groups x 16 lanes: 3 mem instrs / 16 edges, all independent.
//   - bucket_csr shrinks to bucket_dinv (csr/off dead).
//   - dinv stays folded into rows (gemm1 epilogue + agg1 output scale).
// Build pipeline (hist/scan/scatter) and MFMA gemms unchanged from R8.

#define IN_DIM 256
#define HID_DIM 128
#define OUT_DIM 64
#define BSHIFT 7
#define MAXNB 1024      // supports N <= 131072
#define STAGE_CAP 8192  // max edges staged per scatter block (32 KB LDS)

typedef _Float16 half8 __attribute__((ext_vector_type(8)));
typedef float floatx4 __attribute__((ext_vector_type(4)));

// ---- build A: bucket histogram (LDS-privatized) + W^T fp16 conversion ----
__global__ __launch_bounds__(256) void bucket_hist(const int* __restrict__ dst, int E,
                                                   int NB, int* __restrict__ bcnt,
                                                   const float* __restrict__ W1,
                                                   const float* __restrict__ W2,
                                                   __half* __restrict__ Wt1,
                                                   __half* __restrict__ Wt2) {
  __shared__ int h[MAXNB];
  int t = threadIdx.x;
  int gid = blockIdx.x * 256 + t, gsz = gridDim.x * 256;
  // fold in the (tiny) weight transposes
  for (int i = gid; i < IN_DIM * HID_DIM; i += gsz) {
    int n = i / IN_DIM, k = i % IN_DIM;
    Wt1[i] = __float2half(W1[k * HID_DIM + n]);
  }
  for (int i = gid; i < HID_DIM * OUT_DIM; i += gsz) {
    int n = i / HID_DIM, k = i % HID_DIM;
    Wt2[i] = __float2half(W2[k * OUT_DIM + n]);
  }
  for (int i = t; i < MAXNB; i += 256) h[i] = 0;
  __syncthreads();
  for (int i = gid; i < E; i += gsz) atomicAdd(&h[dst[i] >> BSHIFT], 1);
  __syncthreads();
  for (int i = t; i < NB; i += 256) {
    int v = h[i];
    if (v) atomicAdd(&bcnt[i], v);
  }
}

// ---- build B: scan bucket counts; init global cursors ----
__global__ __launch_bounds__(1024) void bucket_scan(const int* __restrict__ bcnt, int NB,
                                                    int E, int* __restrict__ boff,
                                                    int* __restrict__ bcur) {
  __shared__ int sh[1024];
  int t = threadIdx.x;
  int v = (t < NB) ? bcnt[t] : 0;
  sh[t] = v;
  __syncthreads();
  for (int s = 1; s < 1024; s <<= 1) {
    int a = (t >= s) ? sh[t - s] : 0;
    __syncthreads();
    sh[t] += a;
    __syncthreads();
  }
  if (t < NB) {
    int ex = sh[t] - v;
    boff[t] = ex;
    bcur[t] = ex;
  }
  if (t == 0) boff[NB] = E;
}

// ---- build C: LDS-staged counting sort of each chunk, coalesced writeout ----
// pairs[g] = (src<<7)|(dst&127), bucket-contiguous.
__global__ __launch_bounds__(256) void bucket_scatter(const int* __restrict__ src,
                                                      const int* __restrict__ dst, int E,
                                                      int NB, int* __restrict__ bcur,
                                                      int* __restrict__ pairs) {
  __shared__ int hist[MAXNB];
  __shared__ int base_l[MAXNB + 1];  // exclusive scan of hist (LDS slot base)
  __shared__ int base_g[MAXNB];     // this block's run base in global pairs[]
  __shared__ int cur[MAXNB];
  __shared__ int sm[256];
  __shared__ int stage[STAGE_CAP];
  int t = threadIdx.x;
  int chunk = (E + gridDim.x - 1) / gridDim.x;
  int s0 = blockIdx.x * chunk, s1 = min(E, s0 + chunk);
  int cnt = s1 - s0;  // <= STAGE_CAP by launch config

  for (int i = t; i < MAXNB; i += 256) hist[i] = 0;
  __syncthreads();
  for (int i = s0 + t; i < s1; i += 256) atomicAdd(&hist[dst[i] >> BSHIFT], 1);
  __syncthreads();
  // scan 1024 hist entries with 256 threads (4 each)
  {
    int i0 = t * 4;
    int v0 = hist[i0], v1 = hist[i0 + 1], v2 = hist[i0 + 2], v3 = hist[i0 + 3];
    int s = v0 + v1 + v2 + v3;
    sm[t] = s;
    __syncthreads();
    for (int st = 1; st < 256; st <<= 1) {
      int a = (t >= st) ? sm[t - st] : 0;
      __syncthreads();
      sm[t] += a;
      __syncthreads();
    }
    int ex = sm[t] - s;
    base_l[i0] = ex;
    base_l[i0 + 1] = ex + v0;
    base_l[i0 + 2] = ex + v0 + v1;
    base_l[i0 + 3] = ex + v0 + v1 + v2;
    cur[i0] = ex;
    cur[i0 + 1] = ex + v0;
    cur[i0 + 2] = ex + v0 + v1;
    cur[i0 + 3] = ex + v0 + v1 + v2;
    if (v0) base_g[i0] = atomicAdd(&bcur[i0], v0);
    if (v1) base_g[i0 + 1] = atomicAdd(&bcur[i0 + 1], v1);
    if (v2) base_g[i0 + 2] = atomicAdd(&bcur[i0 + 2], v2);
    if (v3) base_g[i0 + 3] = atomicAdd(&bcur[i0 + 3], v3);
    if (t == 0) base_l[MAXNB] = cnt;
  }
  __syncthreads();
  // rank-scatter into LDS stage (packed payload)
  for (int i = s0 + t; i < s1; i += 256) {
    int d = dst[i];
    int bk = d >> BSHIFT;
    int r = atomicAdd(&cur[bk], 1);
    stage[r] = (src[i] << BSHIFT) | (d & ((1 << BSHIFT) - 1));
  }
  __syncthreads();
  // coalesced writeout: slot j -> bucket via binary search on base_l
  for (int j = t; j < cnt; j += 256) {
    int lo = 0, hi = MAXNB;
    while (hi - lo > 1) {
      int mid = (lo + hi) >> 1;
      if (base_l[mid] <= j) lo = mid;
      else hi = mid;
    }
    pairs[base_g[lo] + (j - base_l[lo])] = stage[j];
  }
}

// ---- build D: per-bucket degree -> dinv (csr/off no longer materialized) ----
__global__ __launch_bounds__(256) void bucket_dinv(const int* __restrict__ pairs,
                                                   const int* __restrict__ boff, int N,
                                                   float* __restrict__ dinv) {
  int b = blockIdx.x;
  int t = threadIdx.x;
  __shared__ int ldeg[128];
  if (t < 128) ldeg[t] = 0;
  __syncthreads();
  int e0 = boff[b], e1 = boff[b + 1];
  for (int e = e0 + t; e < e1; e += 256) atomicAdd(&ldeg[pairs[e] & 127], 1);
  __syncthreads();
  int n = (b << BSHIFT) + t;
  if (t < 128 && n < N) dinv[n] = 1.0f / sqrtf((float)(ldeg[t] + 1));
}

// C[M x NC](fp16) = A[M x K] @ W[K x NC] via v_mfma_f32_16x16x32_f16.
// SCALE: multiply output row by rowscale[row] (dinv fold for layer 1).
// BLOCKED: write C column-blocked [NC/16][M][16] (for XCD-partitioned agg).
template <int K, int NC, typename AT, bool SCALE, bool BLOCKED>
__global__ __launch_bounds__(256) void mfma_gemm(const AT* __restrict__ A,
                                                 const __half* __restrict__ Wt,
                                                 __half* __restrict__ C, int M,
                                                 const float* __restrict__ rowscale) {
  constexpr int BK = 32;
  constexpr int STR = BK + 8;  // padded LDS row stride (halves) -> 2-way max
  constexpr int CT = NC / 16;
  __shared__ _Float16 As[128 * STR];
  __shared__ _Float16 Ws[NC * STR];
  int row0 = blockIdx.x * 128;
  int t = threadIdx.x;
  int wave = t >> 6, lane = t & 63, quad = lane >> 4, lr = lane & 15;
  floatx4 acc[2][CT] = {};
  int arow = t >> 1, ako = (t & 1) * 16;
  int grow = row0 + arow;

  for (int k0 = 0; k0 < K; k0 += BK) {
    {
      half8 h0 = {}, h1 = {};
      if (grow < M) {
        if constexpr (sizeof(AT) == 4) {
          const float4* ap = (const float4*)(A + (size_t)grow * K + k0 + ako);
          float4 v0 = ap[0], v1 = ap[1], v2 = ap[2], v3 = ap[3];
          h0[0] = (_Float16)v0.x; h0[1] = (_Float16)v0.y;
          h0[2] = (_Float16)v0.z; h0[3] = (_Float16)v0.w;
          h0[4] = (_Float16)v1.x; h0[5] = (_Float16)v1.y;
          h0[6] = (_Float16)v1.z; h0[7] = (_Float16)v1.w;
          h1[0] = (_Float16)v2.x; h1[1] = (_Float16)v2.y;
          h1[2] = (_Float16)v2.z; h1[3] = (_Float16)v2.w;
          h1[4] = (_Float16)v3.x; h1[5] = (_Float16)v3.y;
          h1[6] = (_Float16)v3.z; h1[7] = (_Float16)v3.w;
        } else {
          const half8* ap = (const half8*)(A + (size_t)grow * K + k0 + ako);
          h0 = ap[0];
          h1 = ap[1];
        }
      }
      *(half8*)&As[arow * STR + ako] = h0;
      *(half8*)&As[arow * STR + ako + 8] = h1;
    }
    if constexpr (NC == 128) {
      int r = t >> 1, ko = (t & 1) * 16;
      const half8* wp = (const half8*)(Wt + (size_t)r * K + k0 + ko);
      *(half8*)&Ws[r * STR + ko] = wp[0];
      *(half8*)&Ws[r * STR + ko + 8] = wp[1];
    } else {  // NC == 64
      int r = t >> 2, ko = (t & 3) * 8;
      *(half8*)&Ws[r * STR + ko] = *(const half8*)(Wt + (size_t)r * K + k0 + ko);
    }
    __syncthreads();
    {
      int a_off = (wave * 32 + lr) * STR + quad * 8;
      half8 a0 = *(const half8*)&As[a_off];
      half8 a1 = *(const half8*)&As[a_off + 16 * STR];
      int b_off = lr * STR + quad * 8;
#pragma unroll
      for (int ct = 0; ct < CT; ct++) {
        half8 bfr = *(const half8*)&Ws[b_off + ct * 16 * STR];
        acc[0][ct] = __builtin_amdgcn_mfma_f32_16x16x32_f16(a0, bfr, acc[0][ct], 0, 0, 0);
        acc[1][ct] = __builtin_amdgcn_mfma_f32_16x16x32_f16(a1, bfr, acc[1][ct], 0, 0, 0);
      }
    }
    __syncthreads();
  }
#pragma unroll
  for (int rt = 0; rt < 2; rt++) {
    int rbase = row0 + wave * 32 + rt * 16 + quad * 4;
#pragma unroll
    for (int i = 0; i < 4; i++) {
      int row = rbase + i;
      if (row < M) {
        float sc = 1.f;
        if constexpr (SCALE) sc = rowscale[row];
#pragma unroll
        for (int ct = 0; ct < CT; ct++) {
          size_t idx;
          if constexpr (BLOCKED) idx = (size_t)ct * M * 16 + (size_t)row * 16 + lr;
          else                   idx = (size_t)row * NC + ct * 16 + lr;
          C[idx] = __float2half(acc[rt][ct][i] * sc);
        }
      }
    }
  }
}

// agg layer 1: block = (bucket b, col-group cg). h1 blocked [8][N][16];
// bid%8 = cg -> pinned to one XCD (verified by R8's FETCH collapse).
// LDS f32 acc[128][17]; 16 edge-groups x 16 col-lanes; ds_add_f32 scatter.
// Epilogue adds self-loop row, applies di*(.)+b, relu, *di (layer-2 fold).
__global__ __launch_bounds__(256) void agg1_kernel(const __half* __restrict__ h,
                                                   const int* __restrict__ pairs,
                                                   const int* __restrict__ boff,
                                                   const float* __restrict__ dinv,
                                                   const float* __restrict__ bias,
                                                   __half* __restrict__ out, int N) {
  __shared__ float acc[128 * 17];
  int cg = blockIdx.x & 7;
  int b = blockIdx.x >> 3;
  int t = threadIdx.x;
  for (int i = t; i < 128 * 17; i += 256) acc[i] = 0.f;
  __syncthreads();
  const _Float16* __restrict__ hp = (const _Float16*)h + (size_t)cg * N * 16;
  int e0 = boff[b], e1 = boff[b + 1];
  int g = t >> 4, c = t & 15;  // 16 groups x 16 lanes
  int e = e0 + g;
  for (; e + 16 < e1; e += 32) {  // x2 unrolled, iterations independent
    int pk0 = __builtin_nontemporal_load(pairs + e);
    int pk1 = __builtin_nontemporal_load(pairs + e + 16);
    float v0 = (float)hp[(size_t)(pk0 >> 7) * 16 + c];
    float v1 = (float)hp[(size_t)(pk1 >> 7) * 16 + c];
    atomicAdd(&acc[(pk0 & 127) * 17 + c], v0);
    atomicAdd(&acc[(pk1 & 127) * 17 + c], v1);
  }
  if (e < e1) {
    int pk = __builtin_nontemporal_load(pairs + e);
    float v = (float)hp[(size_t)(pk >> 7) * 16 + c];
    atomicAdd(&acc[(pk & 127) * 17 + c], v);
  }
  __syncthreads();
  // epilogue: 2 threads per node, 8 cols each
  int nl = t >> 1, c0 = (t & 1) * 8;
  int n = (b << BSHIFT) + nl;
  if (n < N) {
    float di = dinv[n];
    int cb = cg * 16 + c0;
    half8 hs = *(const half8*)(hp + (size_t)n * 16 + c0);  // self-loop (pre-scaled)
    half8 o;
#pragma unroll
    for (int j = 0; j < 8; j++) {
      float a = acc[nl * 17 + c0 + j] + (float)hs[j];
      float r = fmaxf(di * a + bias[cb + j], 0.f) * di;  // *di = layer-2 fold
      o[j] = (_Float16)r;
    }
    __builtin_nontemporal_store(o, (half8*)((_Float16*)out + (size_t)n * HID_DIM + cb));
  }
}

// agg layer 2: same structure; h2 blocked [4][N][16] (slice on 2 XCDs),
// fp32 row-major output, bias only (rows pre-scaled via z16 fold).
__global__ __launch_bounds__(256) void agg2_kernel(const __half* __restrict__ h,
                                                   const int* __restrict__ pairs,
                                                   const int* __restrict__ boff,
                                                   const float* __restrict__ dinv,
                                                   const float* __restrict__ bias,
                                                   float* __restrict__ out, int N) {
  __shared__ float acc[128 * 17];
  int cg = blockIdx.x & 3;
  int b = blockIdx.x >> 2;
  int t = threadIdx.x;
  for (int i = t; i < 128 * 17; i += 256) acc[i] = 0.f;
  __syncthreads();
  const _Float16* __restrict__ hp = (const _Float16*)h + (size_t)cg * N * 16;
  int e0 = boff[b], e1 = boff[b + 1];
  int g = t >> 4, c = t & 15;
  int e = e0 + g;
  for (; e + 16 < e1; e += 32) {
    int pk0 = __builtin_nontemporal_load(pairs + e);
    int pk1 = __builtin_nontemporal_load(pairs + e + 16);
    float v0 = (float)hp[(size_t)(pk0 >> 7) * 16 + c];
    float v1 = (float)hp[(size_t)(pk1 >> 7) * 16 + c];
    atomicAdd(&acc[(pk0 & 127) * 17 + c], v0);
    atomicAdd(&acc[(pk1 & 127) * 17 + c], v1);
  }
  if (e < e1) {
    int pk = __builtin_nontemporal_load(pairs + e);
    float v = (float)hp[(size_t)(pk >> 7) * 16 + c];
    atomicAdd(&acc[(pk & 127) * 17 + c], v);
  }
  __syncthreads();
  int nl = t >> 1, c0 = (t & 1) * 8;
  int n = (b << BSHIFT) + nl;
  if (n < N) {
    float di = dinv[n];
    int cb = cg * 16 + c0;
    half8 hs = *(const half8*)(hp + (size_t)n * 16 + c0);  // self-loop
    float* op = out + (size_t)n * OUT_DIM + cb;
    floatx4 o0, o1;
#pragma unroll
    for (int j = 0; j < 8; j++) {
      float a = acc[nl * 17 + c0 + j] + (float)hs[j];
      float r = di * a + bias[cb + j];
      if (j < 4) o0[j] = r;
      else       o1[j - 4] = r;
    }
    __builtin_nontemporal_store(o0, (floatx4*)op);
    __builtin_nontemporal_store(o1, (floatx4*)(op + 4));
  }
}

extern "C" void kernel_launch(void* const* d_in, const int* in_sizes, int n_in,
                              void* d_out, int out_size, void* d_ws, size_t ws_size,
                              hipStream_t stream) {
  const float* x  = (const float*)d_in[0];
  const int*   ei = (const int*)d_in[1];
  const float* W1 = (const float*)d_in[2];
  const float* b1 = (const float*)d_in[3];
  const float* W2 = (const float*)d_in[4];
  const float* b2 = (const float*)d_in[5];
  float* out = (float*)d_out;

  int N = in_sizes[0] / IN_DIM;
  int E = in_sizes[1] / 2;
  const int* src = ei;
  const int* dst = ei + E;
  int NB = (N + 127) >> BSHIFT;  // 782 for N=100000 (<= MAXNB)

  char* p = (char*)d_ws;
  auto alloc = [&](size_t bytes) {
    char* q = p;
    p += (bytes + 255) & ~(size_t)255;
    return q;
  };
  int*    bcnt  = (int*)alloc((size_t)NB * 4);
  int*    boff  = (int*)alloc((size_t)(NB + 1) * 4);
  int*    bcur  = (int*)alloc((size_t)NB * 4);
  int*    pairs = (int*)alloc((size_t)E * 4);   // packed (src<<7)|(dst&127)
  float*  dinv  = (float*)alloc((size_t)N * 4);
  __half* h1    = (__half*)alloc((size_t)N * HID_DIM * 2);  // blocked [8][N][16]
  __half* z16   = (__half*)alloc((size_t)N * HID_DIM * 2);  // row-major
  __half* Wt1   = (__half*)alloc((size_t)IN_DIM * HID_DIM * 2);
  __half* Wt2   = (__half*)alloc((size_t)HID_DIM * OUT_DIM * 2);
  __half* h2    = h1;  // reused, blocked [4][N][16]
  (void)ws_size; (void)n_in; (void)out_size;

  hipMemsetAsync(bcnt, 0, (size_t)NB * 4, stream);

  bucket_hist<<<256, 256, 0, stream>>>(dst, E, NB, bcnt, W1, W2, Wt1, Wt2);
  bucket_scan<<<1, 1024, 0, stream>>>(bcnt, NB, E, boff, bcur);
  int sblk = max(256, (E + STAGE_CAP - 1) / STAGE_CAP);  // chunk <= STAGE_CAP
  bucket_scatter<<<sblk, 256, 0, stream>>>(src, dst, E, NB, bcur, pairs);
  bucket_dinv<<<NB, 256, 0, stream>>>(pairs, boff, N, dinv);

  int gb = (N + 127) / 128;
  // layer 1: h1 rows pre-scaled by dinv, column-blocked [8][N][16]
  mfma_gemm<IN_DIM, HID_DIM, float, true, true>
      <<<gb, 256, 0, stream>>>(x, Wt1, h1, N, dinv);
  agg1_kernel<<<NB * 8, 256, 0, stream>>>(h1, pairs, boff, dinv, b1, z16, N);

  // layer 2: z16 already carries the dinv row-scale; h2 blocked [4][N][16]
  mfma_gemm<HID_DIM, OUT_DIM, __half, false, true>
      <<<gb, 256, 0, stream>>>(z16, Wt2, h2, N, nullptr);
  agg2_kernel<<<NB * 4, 256, 0, stream>>>(h2, pairs, boff, dinv, b2, out, N);
}

// Round 6
// 425.601 us; speedup vs baseline: 4.4223x; 4.4223x over previous
//
#include <hip/hip_runtime.h>
#include <hip/hip_fp16.h>

// GCN: out = Ahat*(relu(Ahat*(x@W1)+b1))@W2 + b2,  Ahat = D^-1/2 (A+I) D^-1/2
// N=100000, E=1600000, IN=256, HID=128, OUT=64, fp32 in/out.
// R12 = R11 resubmit (round-5 bench died on container acquisition again;
//   identical-source resubmit worked in round 4 -> infra flake, not kernel).
// R11: revert agg to the R6 structure (best measured: agg1=68.6us), keep ONLY
//   the verified-exact dinv fold (gemm1 epilogue scales rows by dinv; agg1
//   stores di*relu(...)): deletes all per-edge dinv gathers from R6's loop.
//   Fix build-kernel occupancy (they ran at 1 block/CU):
//     - bucket_hist grid 256 -> 1024 (4 blocks/CU)
//     - bucket_scatter STAGE_CAP 8192 -> 2048 (LDS 45->25KB), grid -> E/2048
//   R8 taught: XCD col-slicing cuts FETCH 4x but its wave structure loses 3x.
//   R9/R10 taught: LDS-atomic scatter-add is pathological (1063us, VALU 5%).

#define IN_DIM 256
#define HID_DIM 128
#define OUT_DIM 64
#define BSHIFT 7
#define MAXNB 1024      // supports N <= 131072
#define STAGE_CAP 2048  // max edges staged per scatter block (8 KB LDS)

typedef _Float16 half8 __attribute__((ext_vector_type(8)));
typedef float floatx4 __attribute__((ext_vector_type(4)));

// ---- build A: bucket histogram (LDS-privatized) + W^T fp16 conversion ----
__global__ __launch_bounds__(256) void bucket_hist(const int* __restrict__ dst, int E,
                                                   int NB, int* __restrict__ bcnt,
                                                   const float* __restrict__ W1,
                                                   const float* __restrict__ W2,
                                                   __half* __restrict__ Wt1,
                                                   __half* __restrict__ Wt2) {
  __shared__ int h[MAXNB];
  int t = threadIdx.x;
  int gid = blockIdx.x * 256 + t, gsz = gridDim.x * 256;
  // fold in the (tiny) weight transposes
  for (int i = gid; i < IN_DIM * HID_DIM; i += gsz) {
    int n = i / IN_DIM, k = i % IN_DIM;
    Wt1[i] = __float2half(W1[k * HID_DIM + n]);
  }
  for (int i = gid; i < HID_DIM * OUT_DIM; i += gsz) {
    int n = i / HID_DIM, k = i % HID_DIM;
    Wt2[i] = __float2half(W2[k * OUT_DIM + n]);
  }
  for (int i = t; i < MAXNB; i += 256) h[i] = 0;
  __syncthreads();
  for (int i = gid; i < E; i += gsz) atomicAdd(&h[dst[i] >> BSHIFT], 1);
  __syncthreads();
  for (int i = t; i < NB; i += 256) {
    int v = h[i];
    if (v) atomicAdd(&bcnt[i], v);
  }
}

// ---- build B: scan bucket counts; init global cursors; off[N]=E ----
__global__ __launch_bounds__(1024) void bucket_scan(const int* __restrict__ bcnt, int NB,
                                                    int E, int* __restrict__ boff,
                                                    int* __restrict__ bcur,
                                                    int* __restrict__ off, int N) {
  __shared__ int sh[1024];
  int t = threadIdx.x;
  int v = (t < NB) ? bcnt[t] : 0;
  sh[t] = v;
  __syncthreads();
  for (int s = 1; s < 1024; s <<= 1) {
    int a = (t >= s) ? sh[t - s] : 0;
    __syncthreads();
    sh[t] += a;
    __syncthreads();
  }
  if (t < NB) {
    int ex = sh[t] - v;
    boff[t] = ex;
    bcur[t] = ex;
  }
  if (t == 0) {
    boff[NB] = E;
    off[N] = E;
  }
}

// ---- build C: LDS-staged counting sort of each chunk, coalesced writeout ----
// pairs[g] = (src<<7)|(dst&127), bucket-contiguous.
__global__ __launch_bounds__(256) void bucket_scatter(const int* __restrict__ src,
                                                      const int* __restrict__ dst, int E,
                                                      int NB, int* __restrict__ bcur,
                                                      int* __restrict__ pairs) {
  __shared__ int hist[MAXNB];
  __shared__ int base_l[MAXNB + 1];  // exclusive scan of hist (LDS slot base)
  __shared__ int base_g[MAXNB];     // this block's run base in global pairs[]
  __shared__ int cur[MAXNB];
  __shared__ int sm[256];
  __shared__ int stage[STAGE_CAP];
  int t = threadIdx.x;
  int chunk = (E + gridDim.x - 1) / gridDim.x;
  int s0 = blockIdx.x * chunk, s1 = min(E, s0 + chunk);
  int cnt = s1 - s0;  // <= STAGE_CAP by launch config

  for (int i = t; i < MAXNB; i += 256) hist[i] = 0;
  __syncthreads();
  for (int i = s0 + t; i < s1; i += 256) atomicAdd(&hist[dst[i] >> BSHIFT], 1);
  __syncthreads();
  // scan 1024 hist entries with 256 threads (4 each)
  {
    int i0 = t * 4;
    int v0 = hist[i0], v1 = hist[i0 + 1], v2 = hist[i0 + 2], v3 = hist[i0 + 3];
    int s = v0 + v1 + v2 + v3;
    sm[t] = s;
    __syncthreads();
    for (int st = 1; st < 256; st <<= 1) {
      int a = (t >= st) ? sm[t - st] : 0;
      __syncthreads();
      sm[t] += a;
      __syncthreads();
    }
    int ex = sm[t] - s;
    base_l[i0] = ex;
    base_l[i0 + 1] = ex + v0;
    base_l[i0 + 2] = ex + v0 + v1;
    base_l[i0 + 3] = ex + v0 + v1 + v2;
    cur[i0] = ex;
    cur[i0 + 1] = ex + v0;
    cur[i0 + 2] = ex + v0 + v1;
    cur[i0 + 3] = ex + v0 + v1 + v2;
    if (v0) base_g[i0] = atomicAdd(&bcur[i0], v0);
    if (v1) base_g[i0 + 1] = atomicAdd(&bcur[i0 + 1], v1);
    if (v2) base_g[i0 + 2] = atomicAdd(&bcur[i0 + 2], v2);
    if (v3) base_g[i0 + 3] = atomicAdd(&bcur[i0 + 3], v3);
    if (t == 0) base_l[MAXNB] = cnt;
  }
  __syncthreads();
  // rank-scatter into LDS stage (packed payload)
  for (int i = s0 + t; i < s1; i += 256) {
    int d = dst[i];
    int bk = d >> BSHIFT;
    int r = atomicAdd(&cur[bk], 1);
    stage[r] = (src[i] << BSHIFT) | (d & ((1 << BSHIFT) - 1));
  }
  __syncthreads();
  // coalesced writeout: slot j -> bucket via binary search on base_l
  for (int j = t; j < cnt; j += 256) {
    int lo = 0, hi = MAXNB;
    while (hi - lo > 1) {
      int mid = (lo + hi) >> 1;
      if (base_l[mid] <= j) lo = mid;
      else hi = mid;
    }
    pairs[base_g[lo] + (j - base_l[lo])] = stage[j];
  }
}

// ---- build D: per-bucket counting sort -> csr/off/dinv ----
__global__ __launch_bounds__(256) void bucket_csr(const int* __restrict__ pairs,
                                                  const int* __restrict__ boff, int N,
                                                  int* __restrict__ csr,
                                                  int* __restrict__ off,
                                                  float* __restrict__ dinv) {
  int b = blockIdx.x;
  int t = threadIdx.x;
  int n0 = b << BSHIFT;
  int cnt = min(128, N - n0);
  __shared__ int ldeg[128], sh[128], lcur[128];
  if (t < 128) ldeg[t] = 0;
  __syncthreads();
  int e0 = boff[b], e1 = boff[b + 1];
  for (int e = e0 + t; e < e1; e += 256) atomicAdd(&ldeg[pairs[e] & 127], 1);
  __syncthreads();
  int v = (t < 128) ? ldeg[t] : 0;
  if (t < 128) sh[t] = v;
  __syncthreads();
  for (int s = 1; s < 128; s <<= 1) {
    int a = (t < 128 && t >= s) ? sh[t - s] : 0;
    __syncthreads();
    if (t < 128) sh[t] += a;
    __syncthreads();
  }
  if (t < cnt) {
    int ex = sh[t] - v;
    off[n0 + t] = e0 + ex;
    dinv[n0 + t] = 1.0f / sqrtf((float)(v + 1));
    lcur[t] = ex;
  }
  __syncthreads();
  for (int e = e0 + t; e < e1; e += 256) {
    int pk = pairs[e];
    int r = atomicAdd(&lcur[pk & 127], 1);
    csr[e0 + r] = pk >> BSHIFT;
  }
}

// C[M x NC](fp16) = A[M x K] @ W[K x NC] via v_mfma_f32_16x16x32_f16.
// SCALE: multiply output row by rowscale[row] (dinv fold for layer 1).
template <int K, int NC, typename AT, bool SCALE>
__global__ __launch_bounds__(256) void mfma_gemm(const AT* __restrict__ A,
                                                 const __half* __restrict__ Wt,
                                                 __half* __restrict__ C, int M,
                                                 const float* __restrict__ rowscale) {
  constexpr int BK = 32;
  constexpr int STR = BK + 8;  // padded LDS row stride (halves) -> 2-way max
  constexpr int CT = NC / 16;
  __shared__ _Float16 As[128 * STR];
  __shared__ _Float16 Ws[NC * STR];
  int row0 = blockIdx.x * 128;
  int t = threadIdx.x;
  int wave = t >> 6, lane = t & 63, quad = lane >> 4, lr = lane & 15;
  floatx4 acc[2][CT] = {};
  int arow = t >> 1, ako = (t & 1) * 16;
  int grow = row0 + arow;

  for (int k0 = 0; k0 < K; k0 += BK) {
    {
      half8 h0 = {}, h1 = {};
      if (grow < M) {
        if constexpr (sizeof(AT) == 4) {
          const float4* ap = (const float4*)(A + (size_t)grow * K + k0 + ako);
          float4 v0 = ap[0], v1 = ap[1], v2 = ap[2], v3 = ap[3];
          h0[0] = (_Float16)v0.x; h0[1] = (_Float16)v0.y;
          h0[2] = (_Float16)v0.z; h0[3] = (_Float16)v0.w;
          h0[4] = (_Float16)v1.x; h0[5] = (_Float16)v1.y;
          h0[6] = (_Float16)v1.z; h0[7] = (_Float16)v1.w;
          h1[0] = (_Float16)v2.x; h1[1] = (_Float16)v2.y;
          h1[2] = (_Float16)v2.z; h1[3] = (_Float16)v2.w;
          h1[4] = (_Float16)v3.x; h1[5] = (_Float16)v3.y;
          h1[6] = (_Float16)v3.z; h1[7] = (_Float16)v3.w;
        } else {
          const half8* ap = (const half8*)(A + (size_t)grow * K + k0 + ako);
          h0 = ap[0];
          h1 = ap[1];
        }
      }
      *(half8*)&As[arow * STR + ako] = h0;
      *(half8*)&As[arow * STR + ako + 8] = h1;
    }
    if constexpr (NC == 128) {
      int r = t >> 1, ko = (t & 1) * 16;
      const half8* wp = (const half8*)(Wt + (size_t)r * K + k0 + ko);
      *(half8*)&Ws[r * STR + ko] = wp[0];
      *(half8*)&Ws[r * STR + ko + 8] = wp[1];
    } else {  // NC == 64
      int r = t >> 2, ko = (t & 3) * 8;
      *(half8*)&Ws[r * STR + ko] = *(const half8*)(Wt + (size_t)r * K + k0 + ko);
    }
    __syncthreads();
    {
      int a_off = (wave * 32 + lr) * STR + quad * 8;
      half8 a0 = *(const half8*)&As[a_off];
      half8 a1 = *(const half8*)&As[a_off + 16 * STR];
      int b_off = lr * STR + quad * 8;
#pragma unroll
      for (int ct = 0; ct < CT; ct++) {
        half8 bfr = *(const half8*)&Ws[b_off + ct * 16 * STR];
        acc[0][ct] = __builtin_amdgcn_mfma_f32_16x16x32_f16(a0, bfr, acc[0][ct], 0, 0, 0);
        acc[1][ct] = __builtin_amdgcn_mfma_f32_16x16x32_f16(a1, bfr, acc[1][ct], 0, 0, 0);
      }
    }
    __syncthreads();
  }
#pragma unroll
  for (int rt = 0; rt < 2; rt++) {
    int rbase = row0 + wave * 32 + rt * 16 + quad * 4;
#pragma unroll
    for (int i = 0; i < 4; i++) {
      int row = rbase + i;
      if (row < M) {
        float sc = 1.f;
        if constexpr (SCALE) sc = rowscale[row];
#pragma unroll
        for (int ct = 0; ct < CT; ct++) {
          int col = ct * 16 + lr;
          C[(size_t)row * NC + col] = __float2half(acc[rt][ct][i] * sc);
        }
      }
    }
  }
}

// agg layer 1: one wave per node, NC=128, lane covers 2 cols (__half2). x8
// unroll. h rows pre-scaled by dinv (gemm1 epilogue) -> NO per-edge dinv
// loads. Output stores di*relu(...) so layer 2 inherits the row scale.
__global__ __launch_bounds__(256) void agg1_kernel(const __half* __restrict__ h,
                                                   const int* __restrict__ off,
                                                   const int* __restrict__ csr,
                                                   const float* __restrict__ dinv,
                                                   const float* __restrict__ bias,
                                                   __half* __restrict__ out, int N) {
  constexpr int NC = HID_DIM;
  int node = blockIdx.x * 4 + (threadIdx.x >> 6);
  int lane = threadIdx.x & 63;
  if (node >= N) return;
  int c = lane * 2;
  float a0 = 0.f, a1 = 0.f;
  auto gather = [&](int sidx) {
    __half2 hv = *(const __half2*)(h + (size_t)sidx * NC + c);
    float2 f = __half22float2(hv);
    a0 += f.x;
    a1 += f.y;
  };
  gather(node);  // self-loop (row already carries dinv[node])
  int e0 = off[node], e1 = off[node + 1];
  int e = e0;
  for (; e + 8 <= e1; e += 8) {
    int s0 = csr[e], s1 = csr[e + 1], s2 = csr[e + 2], s3 = csr[e + 3];
    int s4 = csr[e + 4], s5 = csr[e + 5], s6 = csr[e + 6], s7 = csr[e + 7];
    gather(s0); gather(s1); gather(s2); gather(s3);
    gather(s4); gather(s5); gather(s6); gather(s7);
  }
  for (; e + 4 <= e1; e += 4) {
    int s0 = csr[e], s1 = csr[e + 1], s2 = csr[e + 2], s3 = csr[e + 3];
    gather(s0); gather(s1); gather(s2); gather(s3);
  }
  for (; e < e1; e++) gather(csr[e]);
  float di = dinv[node];
  float r0 = fmaxf(di * a0 + bias[c], 0.f) * di;      // trailing *di = L2 fold
  float r1 = fmaxf(di * a1 + bias[c + 1], 0.f) * di;
  *(__half2*)(out + (size_t)node * NC + c) = __floats2half2_rn(r0, r1);
}

// agg layer 2: NC=64 -> half-wave per node (32 lanes x __half2). x4 unroll.
// Rows pre-scaled via z16 fold -> no per-edge dinv loads.
__global__ __launch_bounds__(256) void agg2_kernel(const __half* __restrict__ h,
                                                   const int* __restrict__ off,
                                                   const int* __restrict__ csr,
                                                   const float* __restrict__ dinv,
                                                   const float* __restrict__ bias,
                                                   float* __restrict__ out, int N) {
  constexpr int NC = OUT_DIM;
  int node = blockIdx.x * 8 + (threadIdx.x >> 5);
  int hl = threadIdx.x & 31;
  if (node >= N) return;
  int c = hl * 2;
  float a0 = 0.f, a1 = 0.f;
  auto gather = [&](int sidx) {
    __half2 hv = *(const __half2*)(h + (size_t)sidx * NC + c);
    float2 f = __half22float2(hv);
    a0 += f.x;
    a1 += f.y;
  };
  gather(node);
  int e0 = off[node], e1 = off[node + 1];
  int e = e0;
  for (; e + 4 <= e1; e += 4) {
    int s0 = csr[e], s1 = csr[e + 1], s2 = csr[e + 2], s3 = csr[e + 3];
    gather(s0); gather(s1); gather(s2); gather(s3);
  }
  for (; e < e1; e++) gather(csr[e]);
  float di = dinv[node];
  out[(size_t)node * NC + c] = di * a0 + bias[c];
  out[(size_t)node * NC + c + 1] = di * a1 + bias[c + 1];
}

extern "C" void kernel_launch(void* const* d_in, const int* in_sizes, int n_in,
                              void* d_out, int out_size, void* d_ws, size_t ws_size,
                              hipStream_t stream) {
  const float* x  = (const float*)d_in[0];
  const int*   ei = (const int*)d_in[1];
  const float* W1 = (const float*)d_in[2];
  const float* b1 = (const float*)d_in[3];
  const float* W2 = (const float*)d_in[4];
  const float* b2 = (const float*)d_in[5];
  float* out = (float*)d_out;

  int N = in_sizes[0] / IN_DIM;
  int E = in_sizes[1] / 2;
  const int* src = ei;
  const int* dst = ei + E;
  int NB = (N + 127) >> BSHIFT;  // 782 for N=100000 (<= MAXNB)

  char* p = (char*)d_ws;
  auto alloc = [&](size_t bytes) {
    char* q = p;
    p += (bytes + 255) & ~(size_t)255;
    return q;
  };
  int*    bcnt  = (int*)alloc((size_t)NB * 4);
  int*    boff  = (int*)alloc((size_t)(NB + 1) * 4);
  int*    bcur  = (int*)alloc((size_t)NB * 4);
  int*    pairs = (int*)alloc((size_t)E * 4);   // packed (src<<7)|(dst&127)
  int*    csr   = (int*)alloc((size_t)E * 4);
  int*    off   = (int*)alloc((size_t)(N + 1) * 4);
  float*  dinv  = (float*)alloc((size_t)N * 4);
  __half* h1    = (__half*)alloc((size_t)N * HID_DIM * 2);  // reused as h2
  __half* z16   = (__half*)alloc((size_t)N * HID_DIM * 2);
  __half* Wt1   = (__half*)alloc((size_t)IN_DIM * HID_DIM * 2);
  __half* Wt2   = (__half*)alloc((size_t)HID_DIM * OUT_DIM * 2);
  __half* h2    = h1;
  (void)ws_size; (void)n_in; (void)out_size;

  hipMemsetAsync(bcnt, 0, (size_t)NB * 4, stream);

  // build: occupancy-fixed grids (was 256 blocks = 1 block/CU)
  bucket_hist<<<1024, 256, 0, stream>>>(dst, E, NB, bcnt, W1, W2, Wt1, Wt2);
  bucket_scan<<<1, 1024, 0, stream>>>(bcnt, NB, E, boff, bcur, off, N);
  int sblk = (E + STAGE_CAP - 1) / STAGE_CAP;  // 782 blocks, chunk <= 2048
  bucket_scatter<<<sblk, 256, 0, stream>>>(src, dst, E, NB, bcur, pairs);
  bucket_csr<<<NB, 256, 0, stream>>>(pairs, boff, N, csr, off, dinv);

  int gb = (N + 127) / 128;
  // layer 1: h1 rows pre-scaled by dinv (SCALE=true)
  mfma_gemm<IN_DIM, HID_DIM, float, true><<<gb, 256, 0, stream>>>(x, Wt1, h1, N, dinv);
  agg1_kernel<<<(N + 3) / 4, 256, 0, stream>>>(h1, off, csr, dinv, b1, z16, N);

  // layer 2: z16 already carries the dinv row-scale
  mfma_gemm<HID_DIM, OUT_DIM, __half, false><<<gb, 256, 0, stream>>>(z16, Wt2, h2, N, nullptr);
  agg2_kernel<<<(N + 7) / 8, 256, 0, stream>>>(h2, off, csr, dinv, b2, out, N);
}